// Round 16
// baseline (520.987 us; speedup 1.0000x reference)
//
#include <hip/hip_runtime.h>
#include <hip/hip_bf16.h>
#include <cstdint>
#include <cstddef>

#define HD_B   4
#define SEQ    4096
#define CDIM   768
#define HEADS  12
#define HDIM   64
#define MROWS  (HD_B * SEQ)     // 16384
#define QSCALE 0.125f
#define EPSV   1e-6f

typedef __attribute__((ext_vector_type(8))) short  short8v;  // 8 x bf16
typedef __attribute__((ext_vector_type(4))) float  f32x4;

__device__ __forceinline__ unsigned short f2b(float f) {
    unsigned int u = __float_as_uint(f);
    u += 0x7FFFu + ((u >> 16) & 1u);   // RNE
    return (unsigned short)(u >> 16);
}
__device__ __forceinline__ float b2f(unsigned short b) {
    return __uint_as_float(((unsigned int)b) << 16);
}
__device__ __forceinline__ float phi_f(float x) {  // elu(x)+1
    return x > 0.f ? x + 1.f : __expf(x);
}

#define GLOAD_LDS16(g, l)                                             \
    __builtin_amdgcn_global_load_lds(                                 \
        (__attribute__((address_space(1))) void*)(void*)(g),          \
        (__attribute__((address_space(3))) void*)(l), 16, 0, 0)

#define VMW20() asm volatile("s_waitcnt vmcnt(20)" ::: "memory")
#define VMW12() asm volatile("s_waitcnt vmcnt(12)" ::: "memory")
#define VMW8()  asm volatile("s_waitcnt vmcnt(8)"  ::: "memory")
#define VMW4()  asm volatile("s_waitcnt vmcnt(4)"  ::: "memory")
#define VMW0()  asm volatile("s_waitcnt vmcnt(0)"  ::: "memory")
#define LGW()   asm volatile("s_waitcnt lgkmcnt(0)" ::: "memory")
#define SB()    do { __builtin_amdgcn_sched_barrier(0);               \
                     __builtin_amdgcn_s_barrier();                    \
                     __builtin_amdgcn_sched_barrier(0); } while (0)

// ---------------------------------------------------------------- weight cvt
// dst contiguous: [Wq | Wk | Wv | Wp]
__global__ void wcvt_all(const float* __restrict__ wq, const float* __restrict__ wk,
                         const float* __restrict__ wv, const float* __restrict__ wp,
                         unsigned short* __restrict__ dst) {
    const int y = blockIdx.y;
    const float* src = (y == 0) ? wq : (y == 1) ? wk : (y == 2) ? wv : wp;
    const int i = blockIdx.x * 256 + threadIdx.x;
    float4 v = reinterpret_cast<const float4*>(src)[i];
    ushort4 o;
    o.x = f2b(v.x); o.y = f2b(v.y); o.z = f2b(v.z); o.w = f2b(v.w);
    reinterpret_cast<ushort4*>(dst + (size_t)y * (CDIM * CDIM))[i] = o;
}

// ---------------------------------------------------------------- pipelined projection
// R13 schedule + A prefetch deepened to 2 iterations (double reg buffer fAa/fAb,
// aload issued at loop top). Counted vmcnt audited:
//   steady top: [B(t)4, A(t+1)8, B(t+1)4] +aload(t+2)8 = 24 -> VMW20 drains B(t)
//   post-compute: [A(t+1)8, B(t+1)4, A(t+2)8] = 20 -> VMW12 drains A(t+1)
//   t=NT-2: top 16 -> VMW12; post 12 -> VMW4.  t=NT-1: VMW0.
template <int EPI, int NC>
__device__ __forceinline__ void proj_body(
    const float* __restrict__ A32,
    const unsigned short* __restrict__ Bp,
    const float* __restrict__ b0, const float* __restrict__ b1,
    unsigned short* __restrict__ o0, unsigned short* __restrict__ o1)
{
    constexpr int K  = CDIM;                 // 768
    constexpr int T  = NC * 128;
    constexpr int NT = K / 64;               // 12 (even)

    __shared__ __align__(16) char smem[49152];
    char* As = smem;                          // 16 KB, single buffer
    // Bs[buf] at 16384 + buf*16384

    const int tid  = threadIdx.x;
    const int lane = tid & 63;
    const int w    = tid >> 6;
    const int wr   = w >> 1, wc = w & 1;

    const int bid  = blockIdx.x;
    const int s    = (bid & 7) * (T >> 3) + (bid >> 3);
    const int colp = s % NC;
    const int rowp = s / NC;
    const int brow = rowp * 128;
    const int bcol = colp * 128;

    const int r8  = lane >> 3;
    const int c8e = ((lane & 7) ^ r8) << 3;
    const int ar  = lane >> 4;
    const int ac  = (lane & 15) << 2;
    const int fr  = lane & 15;
    const int hi4 = lane >> 4;

    f32x4 acc[4][4];
#pragma unroll
    for (int i = 0; i < 4; ++i)
#pragma unroll
        for (int j = 0; j < 4; ++j)
            acc[i][j] = (f32x4){0.f, 0.f, 0.f, 0.f};

    auto stageB = [&](int buf, int kt) {
        char* dst = smem + 16384 + buf * 16384;
#pragma unroll
        for (int g = 0; g < 4; ++g) {
            const unsigned short* src =
                Bp + (size_t)(bcol + w * 32 + g * 8 + r8) * K + kt * 64 + c8e;
            GLOAD_LDS16(src, dst + (w * 32 + g * 8) * 128);
        }
    };

    float4 fAa[8], fAb[8];
    auto aloadTo = [&](int kt, float4 (&dst)[8]) {
#pragma unroll
        for (int j = 0; j < 8; ++j)
            dst[j] = *(const float4*)(A32 + (size_t)(brow + w * 32 + j * 4 + ar) * K
                                      + kt * 64 + ac);
    };
    auto awriteFrom = [&](const float4 (&src)[8]) {
#pragma unroll
        for (int j = 0; j < 8; ++j) {
            const int row = w * 32 + j * 4 + ar;
            unsigned int p0, p1;
            asm("v_cvt_pk_bf16_f32 %0, %1, %2" : "=v"(p0) : "v"(src[j].x), "v"(src[j].y));
            asm("v_cvt_pk_bf16_f32 %0, %1, %2" : "=v"(p1) : "v"(src[j].z), "v"(src[j].w));
            uint2 pk; pk.x = p0; pk.y = p1;
            *(uint2*)(As + row * 128 + ((ac << 1) ^ ((row & 7) << 4))) = pk;
        }
    };
    auto compute = [&](int bbuf) {
        const char* Bb = smem + 16384 + bbuf * 16384;
        short8v a[4][2];
#pragma unroll
        for (int i = 0; i < 4; ++i) {
            const int row = wr * 64 + i * 16 + fr;
#pragma unroll
            for (int ks = 0; ks < 2; ++ks)
                a[i][ks] = *(const short8v*)(As + row * 128 +
                              ((((ks << 2) + hi4) ^ (row & 7)) << 4));
        }
#pragma unroll
        for (int j = 0; j < 4; ++j) {
            const int row = wc * 64 + j * 16 + fr;
            short8v bb0 = *(const short8v*)(Bb + row * 128 + ((hi4 ^ (row & 7)) << 4));
            short8v bb1 = *(const short8v*)(Bb + row * 128 + (((4 + hi4) ^ (row & 7)) << 4));
#pragma unroll
            for (int i = 0; i < 4; ++i) {
                acc[i][j] = __builtin_amdgcn_mfma_f32_16x16x32_bf16(a[i][0], bb0, acc[i][j], 0, 0, 0);
                acc[i][j] = __builtin_amdgcn_mfma_f32_16x16x32_bf16(a[i][1], bb1, acc[i][j], 0, 0, 0);
            }
        }
    };

    // prologue: A(0) -> LDS; [B(0), A(1), B(1)] = 16 left in flight
    aloadTo(0, fAa);
    stageB(0, 0);
    VMW4();            // drain A8(0), keep B4(0)
    awriteFrom(fAa);
    aloadTo(1, fAb);
    stageB(1, 1);
    LGW();
    SB();

    // iteration body; nx2 receives A(t+2), nx1 holds A(t+1)
    auto iter = [&](int t, float4 (&nx2)[8], const float4 (&nx1)[8]) {
        const int c = t & 1;
        if (t < NT - 2) aloadTo(t + 2, nx2);
        __builtin_amdgcn_sched_barrier(0);
        if (t == NT - 1)      { VMW0(); }
        else if (t == NT - 2) { VMW12(); }
        else                  { VMW20(); }
        SB();
        compute(c);
        SB();
        if (t < NT - 1) {
            if (t == NT - 2) { VMW4(); } else { VMW12(); }
            awriteFrom(nx1);
            if (t < NT - 2) stageB(c, t + 2);
            LGW();
        }
    };
#pragma unroll
    for (int tt = 0; tt < NT / 2; ++tt) {
        iter(2 * tt,     fAa, fAb);   // A(t+2)->fAa ; write A(t+1) from fAb
        iter(2 * tt + 1, fAb, fAa);
    }

    // ---------------- epilogue
    float* ep = (float*)(void*)smem + w * (16 * 68);
    const int rr = lane >> 2;
    const int cb = (lane & 3) * 4;
    const bool isV = (EPI == 1) && (colp >= 6);
    const float* bptr = (EPI == 0) ? (b0 + bcol)
                        : (isV ? (b1 + (bcol - 768)) : (b0 + bcol));
    const int colbase = ((EPI == 1 && isV) ? bcol - 768 : bcol) + wc * 64;
    unsigned short* o16 = (EPI == 1 && isV) ? o1 : o0;

    float4 bb[4];
#pragma unroll
    for (int q = 0; q < 4; ++q)
        bb[q] = *(const float4*)&bptr[wc * 64 + q * 16 + cb];

#pragma unroll
    for (int i = 0; i < 4; ++i) {
#pragma unroll
        for (int j = 0; j < 4; ++j)
#pragma unroll
            for (int r = 0; r < 4; ++r)
                ep[(hi4 * 4 + r) * 68 + j * 16 + fr] = acc[i][j][r];
#pragma unroll
        for (int q = 0; q < 4; ++q) {
            const int cc = q * 16 + cb;
            f32x4 v = *(const f32x4*)&ep[rr * 68 + cc];
            const int rg = brow + wr * 64 + i * 16 + rr;
            const float4 bq = bb[q];
            ushort4 ov;
            if (EPI == 0) {
                ov.x = f2b(phi_f((v[0] + bq.x) * QSCALE));
                ov.y = f2b(phi_f((v[1] + bq.y) * QSCALE));
                ov.z = f2b(phi_f((v[2] + bq.z) * QSCALE));
                ov.w = f2b(phi_f((v[3] + bq.w) * QSCALE));
            } else if (!isV) {
                ov.x = f2b(phi_f(v[0] + bq.x));
                ov.y = f2b(phi_f(v[1] + bq.y));
                ov.z = f2b(phi_f(v[2] + bq.z));
                ov.w = f2b(phi_f(v[3] + bq.w));
            } else {
                ov.x = f2b(v[0] + bq.x);
                ov.y = f2b(v[1] + bq.y);
                ov.z = f2b(v[2] + bq.z);
                ov.w = f2b(v[3] + bq.w);
            }
            *(ushort4*)(o16 + (size_t)rg * 768 + (colbase + cc)) = ov;
        }
    }
}

__global__ __launch_bounds__(256, 3) void g_q(
    const float* __restrict__ xq, const unsigned short* __restrict__ wq,
    const float* __restrict__ bq, unsigned short* __restrict__ qphi)
{
    proj_body<0, 6>(xq, wq, bq, nullptr, qphi, nullptr);
}

__global__ __launch_bounds__(256, 3) void g_kv(
    const float* __restrict__ xkv, const unsigned short* __restrict__ wkv,
    const float* __restrict__ bk, const float* __restrict__ bv,
    unsigned short* __restrict__ kphi, unsigned short* __restrict__ v16)
{
    proj_body<1, 12>(xkv, wkv, bk, bv, kphi, v16);
}

// ---------------------------------------------------------------- output projection
// R12/R13-proven: both operands via global_load_lds, double-buffered (64 KB),
// stage-ahead-2, counted vmcnt(8), raw barriers.
__global__ __launch_bounds__(256) void g_out(
    const unsigned short* __restrict__ A16,
    const unsigned short* __restrict__ Bp,
    const float* __restrict__ bias,
    float* __restrict__ outp)
{
    constexpr int K  = CDIM;
    constexpr int NT = K / 64;               // 12
    __shared__ __align__(16) char smem[65536];

    const int tid  = threadIdx.x;
    const int lane = tid & 63;
    const int w    = tid >> 6;
    const int wr   = w >> 1, wc = w & 1;

    const int bid  = blockIdx.x;
    const int s    = (bid & 7) * (768 >> 3) + (bid >> 3);
    const int colp = s % 6;
    const int rowp = s / 6;
    const int brow = rowp * 128;
    const int bcol = colp * 128;

    const int r8  = lane >> 3;
    const int c8e = ((lane & 7) ^ r8) << 3;
    const int fr  = lane & 15;
    const int hi4 = lane >> 4;

    f32x4 acc[4][4];
#pragma unroll
    for (int i = 0; i < 4; ++i)
#pragma unroll
        for (int j = 0; j < 4; ++j)
            acc[i][j] = (f32x4){0.f, 0.f, 0.f, 0.f};

    auto stageA = [&](int buf, int kt) {
        char* dst = smem + buf * 16384;
#pragma unroll
        for (int g = 0; g < 4; ++g) {
            const unsigned short* src =
                A16 + (size_t)(brow + w * 32 + g * 8 + r8) * K + kt * 64 + c8e;
            GLOAD_LDS16(src, dst + (w * 32 + g * 8) * 128);
        }
    };
    auto stageB = [&](int buf, int kt) {
        char* dst = smem + 32768 + buf * 16384;
#pragma unroll
        for (int g = 0; g < 4; ++g) {
            const unsigned short* src =
                Bp + (size_t)(bcol + w * 32 + g * 8 + r8) * K + kt * 64 + c8e;
            GLOAD_LDS16(src, dst + (w * 32 + g * 8) * 128);
        }
    };
    auto compute = [&](int buf) {
        const char* Ab = smem + buf * 16384;
        const char* Bb = smem + 32768 + buf * 16384;
        short8v a[4][2], b[4][2];
#pragma unroll
        for (int i = 0; i < 4; ++i) {
            const int row = wr * 64 + i * 16 + fr;
#pragma unroll
            for (int ks = 0; ks < 2; ++ks)
                a[i][ks] = *(const short8v*)(Ab + row * 128 +
                              ((((ks << 2) + hi4) ^ (row & 7)) << 4));
        }
#pragma unroll
        for (int j = 0; j < 4; ++j) {
            const int row = wc * 64 + j * 16 + fr;
#pragma unroll
            for (int ks = 0; ks < 2; ++ks)
                b[j][ks] = *(const short8v*)(Bb + row * 128 +
                              ((((ks << 2) + hi4) ^ (row & 7)) << 4));
        }
#pragma unroll
        for (int i = 0; i < 4; ++i)
#pragma unroll
            for (int j = 0; j < 4; ++j) {
                acc[i][j] = __builtin_amdgcn_mfma_f32_16x16x32_bf16(a[i][0], b[j][0], acc[i][j], 0, 0, 0);
                acc[i][j] = __builtin_amdgcn_mfma_f32_16x16x32_bf16(a[i][1], b[j][1], acc[i][j], 0, 0, 0);
            }
    };

    stageA(0, 0); stageB(0, 0);
    stageA(1, 1); stageB(1, 1);
    for (int t = 0; t < NT; ++t) {
        const int c = t & 1;
        if (t == NT - 1) { VMW0(); } else { VMW8(); }
        SB();
        compute(c);
        SB();
        if (t < NT - 2) { stageA(c, t + 2); stageB(c, t + 2); }
    }

    float* ep = (float*)(void*)smem + w * (16 * 68);
    const int rr = lane >> 2;
    const int cb = (lane & 3) * 4;
    float4 bb[4];
#pragma unroll
    for (int q = 0; q < 4; ++q)
        bb[q] = *(const float4*)&bias[bcol + wc * 64 + q * 16 + cb];
#pragma unroll
    for (int i = 0; i < 4; ++i) {
#pragma unroll
        for (int j = 0; j < 4; ++j)
#pragma unroll
            for (int r = 0; r < 4; ++r)
                ep[(hi4 * 4 + r) * 68 + j * 16 + fr] = acc[i][j][r];
#pragma unroll
        for (int q = 0; q < 4; ++q) {
            const int cc = q * 16 + cb;
            f32x4 v = *(const f32x4*)&ep[rr * 68 + cc];
            const int rg = brow + wr * 64 + i * 16 + rr;
            const int cg = bcol + wc * 64 + cc;
            const float4 bq = bb[q];
            float4 ov;
            ov.x = v[0] + bq.x; ov.y = v[1] + bq.y;
            ov.z = v[2] + bq.z; ov.w = v[3] + bq.w;
            *(float4*)(outp + (size_t)rg * 768 + cg) = ov;
        }
    }
}

// ---------------------------------------------------------------- KV state (R13-exact)
#define KVCH   128
#define KVITER 2
#define NCHUNK 16   // SEQ / (KVCH*KVITER)

__global__ __launch_bounds__(256, 3) void kv_part(
    const unsigned short* __restrict__ kphi,
    const unsigned short* __restrict__ vmat,
    float* __restrict__ part)
{
    const int bh = blockIdx.y;
    const int b  = bh / HEADS, h = bh % HEADS;
    const int c  = blockIdx.x;
    __shared__ unsigned short Kl[KVCH][HDIM];  // 16 KB (bf16)
    __shared__ float Vl[KVCH][HDIM];           // 32 KB
    const int t  = threadIdx.x;
    const int i  = t >> 2;
    const int jb = t & 3;

    float acc[16];
#pragma unroll
    for (int jj = 0; jj < 16; ++jj) acc[jj] = 0.f;
    float ksum = 0.f;

    for (int it = 0; it < KVITER; ++it) {
        const size_t rbase = (size_t)b * SEQ + (size_t)c * (KVCH * KVITER) + it * KVCH;
        __syncthreads();
        for (int l = 0; l < KVCH / 32; ++l) {
            int row = l * 32 + (t >> 3);
            int col = (t & 7) << 3;
            const size_t g = (rbase + row) * CDIM + h * HDIM + col;
            int4 kk = *(const int4*)(kphi + g);
            int4 vv = *(const int4*)(vmat + g);
            *(int4*)&Kl[row][col] = kk;
            const unsigned short* vp = (const unsigned short*)&vv;
            float4 lo, hi;
            lo.x = b2f(vp[0]); lo.y = b2f(vp[1]); lo.z = b2f(vp[2]); lo.w = b2f(vp[3]);
            hi.x = b2f(vp[4]); hi.y = b2f(vp[5]); hi.z = b2f(vp[6]); hi.w = b2f(vp[7]);
            *(float4*)&Vl[row][col]     = lo;
            *(float4*)&Vl[row][col + 4] = hi;
        }
        __syncthreads();
        for (int n = 0; n < KVCH; ++n) {
            float kf = b2f(Kl[n][i]);
            const float4* vr = (const float4*)&Vl[n][jb * 16];
            float4 v0 = vr[0], v1 = vr[1], v2 = vr[2], v3 = vr[3];
            acc[0]  += kf * v0.x; acc[1]  += kf * v0.y; acc[2]  += kf * v0.z; acc[3]  += kf * v0.w;
            acc[4]  += kf * v1.x; acc[5]  += kf * v1.y; acc[6]  += kf * v1.z; acc[7]  += kf * v1.w;
            acc[8]  += kf * v2.x; acc[9]  += kf * v2.y; acc[10] += kf * v2.z; acc[11] += kf * v2.w;
            acc[12] += kf * v3.x; acc[13] += kf * v3.y; acc[14] += kf * v3.z; acc[15] += kf * v3.w;
            ksum += kf;
        }
    }
    float* op = part + ((size_t)c * 48 + bh) * 4160;
#pragma unroll
    for (int jj = 0; jj < 16; ++jj) op[i * 64 + jb * 16 + jj] = acc[jj];
    if (jb == 0) op[4096 + i] = ksum;
}

__global__ void kv_finalize(const float* __restrict__ part, float* __restrict__ kv) {
    int idx = blockIdx.x * 256 + threadIdx.x;
    if (idx >= 48 * 4160) return;
    float s = 0.f;
    for (int c = 0; c < NCHUNK; ++c) s += part[(size_t)c * 48 * 4160 + idx];
    kv[idx] = s;
}

// ---------------------------------------------------------------- apply
__global__ __launch_bounds__(256) void attn_apply(
    const unsigned short* __restrict__ qphi,
    const float* __restrict__ kv,
    unsigned short* __restrict__ attn)
{
    const int h  = blockIdx.y;
    const int m0 = blockIdx.x * 64;
    const int b  = m0 >> 12;
    const int bh = b * HEADS + h;
    __shared__ float kvs[HDIM][HDIM];
    __shared__ float ksums[HDIM];
    __shared__ unsigned short ql[64][HDIM];
    const int t = threadIdx.x;
    const float* kvp = kv + (size_t)bh * 4160;
#pragma unroll
    for (int it = 0; it < 4; ++it) {
        int e = it * 1024 + t * 4;
        *(float4*)&kvs[e >> 6][e & 63] = *(const float4*)&kvp[e];
    }
    if (t < 64) ksums[t] = kvp[4096 + t];
#pragma unroll
    for (int it = 0; it < 2; ++it) {
        int row = it * 32 + (t >> 3);
        int col = (t & 7) << 3;
        *(int4*)&ql[row][col] =
            *(const int4*)(qphi + (size_t)(m0 + row) * CDIM + h * HDIM + col);
    }
    __syncthreads();

    const int r  = t >> 2;
    const int jb = t & 3;
    float acc[16];
#pragma unroll
    for (int jj = 0; jj < 16; ++jj) acc[jj] = 0.f;
    float z = 0.f;
    for (int q8 = 0; q8 < 8; ++q8) {
        short8v qv = *(const short8v*)&ql[r][q8 * 8];
#pragma unroll
        for (int dd = 0; dd < 8; ++dd) {
            float qd = b2f((unsigned short)qv[dd]);
            int d = q8 * 8 + dd;
            const float4* kr = (const float4*)&kvs[d][jb * 16];
            float4 k0 = kr[0], k1 = kr[1], k2 = kr[2], k3 = kr[3];
            acc[0]  += qd * k0.x; acc[1]  += qd * k0.y; acc[2]  += qd * k0.z; acc[3]  += qd * k0.w;
            acc[4]  += qd * k1.x; acc[5]  += qd * k1.y; acc[6]  += qd * k1.z; acc[7]  += qd * k1.w;
            acc[8]  += qd * k2.x; acc[9]  += qd * k2.y; acc[10] += qd * k2.z; acc[11] += qd * k2.w;
            acc[12] += qd * k3.x; acc[13] += qd * k3.y; acc[14] += qd * k3.z; acc[15] += qd * k3.w;
            z += qd * ksums[d];
        }
    }
    const float inv = 1.f / (z + EPSV);
    unsigned short* op = attn + (size_t)(m0 + r) * CDIM + h * HDIM + jb * 16;
#pragma unroll
    for (int jj = 0; jj < 16; ++jj) op[jj] = f2b(acc[jj] * inv);
}

// ---------------------------------------------------------------- launch
extern "C" void kernel_launch(void* const* d_in, const int* in_sizes, int n_in,
                              void* d_out, int out_size, void* d_ws, size_t ws_size,
                              hipStream_t stream)
{
    const float* x_q  = (const float*)d_in[0];
    const float* x_kv = (const float*)d_in[1];
    const float* Wq   = (const float*)d_in[2];
    const float* bq   = (const float*)d_in[3];
    const float* Wk   = (const float*)d_in[4];
    const float* bk   = (const float*)d_in[5];
    const float* Wv   = (const float*)d_in[6];
    const float* bv   = (const float*)d_in[7];
    const float* Wp   = (const float*)d_in[8];
    const float* bp   = (const float*)d_in[9];
    float* out = (float*)d_out;

    char* ws = (char*)d_ws;
    size_t off = 0;
    auto alloc = [&](size_t bytes) -> char* {
        char* p = ws + off;
        off += (bytes + 255) & ~(size_t)255;
        return p;
    };
    const size_t xelems = (size_t)MROWS * CDIM;
    const size_t welems = (size_t)CDIM * CDIM;

    // weights contiguous: [Wq, Wk, Wv, Wp]
    unsigned short* w16    = (unsigned short*)alloc(4 * welems * 2);
    unsigned short* wkv16  = w16 + welems;          // [Wk;Wv] stacked
    unsigned short* wp16   = w16 + 3 * welems;
    unsigned short* qphi   = (unsigned short*)alloc(xelems * 2);
    unsigned short* kphi   = (unsigned short*)alloc(xelems * 2);
    unsigned short* v16    = (unsigned short*)alloc(xelems * 2);
    unsigned short* attn16 = (unsigned short*)alloc(xelems * 2);
    float* part = (float*)alloc((size_t)NCHUNK * 48 * 4160 * 4);
    float* kvf  = (float*)alloc((size_t)48 * 4160 * 4);

    wcvt_all<<<dim3(576, 4), 256, 0, stream>>>(Wq, Wk, Wv, Wp, w16);

    // Q projection: pipelined (A 2-deep), 768 blocks
    g_q<<<768, 256, 0, stream>>>(x_q, w16, bq, qphi);

    // fused K|V projection: pipelined (A 2-deep), 1536 blocks
    g_kv<<<1536, 256, 0, stream>>>(x_kv, wkv16, bk, bv, kphi, v16);

    kv_part<<<dim3(NCHUNK, 48), 256, 0, stream>>>(kphi, v16, part);
    kv_finalize<<<(48 * 4160 + 255) / 256, 256, 0, stream>>>(part, kvf);
    attn_apply<<<dim3(MROWS / 64, HEADS), 256, 0, stream>>>(qphi, kvf, attn16);

    // output projection: pipelined both-gload, 768 blocks
    g_out<<<768, 256, 0, stream>>>(attn16, wp16, bp, out);
}

// Round 17
// 200.456 us; speedup vs baseline: 2.5990x; 2.5990x over previous
//
#include <hip/hip_runtime.h>
#include <hip/hip_bf16.h>
#include <cstdint>
#include <cstddef>

#define HD_B   4
#define SEQ    4096
#define CDIM   768
#define HEADS  12
#define HDIM   64
#define MROWS  (HD_B * SEQ)     // 16384
#define QSCALE 0.125f
#define EPSV   1e-6f

typedef __attribute__((ext_vector_type(8))) short  short8v;  // 8 x bf16
typedef __attribute__((ext_vector_type(4))) float  f32x4;

__device__ __forceinline__ unsigned short f2b(float f) {
    unsigned int u = __float_as_uint(f);
    u += 0x7FFFu + ((u >> 16) & 1u);   // RNE
    return (unsigned short)(u >> 16);
}
__device__ __forceinline__ float b2f(unsigned short b) {
    return __uint_as_float(((unsigned int)b) << 16);
}
__device__ __forceinline__ float phi_f(float x) {  // elu(x)+1
    return x > 0.f ? x + 1.f : __expf(x);
}

#define GLOAD_LDS16(g, l)                                             \
    __builtin_amdgcn_global_load_lds(                                 \
        (__attribute__((address_space(1))) void*)(void*)(g),          \
        (__attribute__((address_space(3))) void*)(l), 16, 0, 0)

#define VMW12() asm volatile("s_waitcnt vmcnt(12)" ::: "memory")
#define VMW8()  asm volatile("s_waitcnt vmcnt(8)"  ::: "memory")
#define VMW4()  asm volatile("s_waitcnt vmcnt(4)"  ::: "memory")
#define VMW0()  asm volatile("s_waitcnt vmcnt(0)"  ::: "memory")
#define LGW()   asm volatile("s_waitcnt lgkmcnt(0)" ::: "memory")
#define SB()    do { __builtin_amdgcn_sched_barrier(0);               \
                     __builtin_amdgcn_s_barrier();                    \
                     __builtin_amdgcn_sched_barrier(0); } while (0)

// ---------------------------------------------------------------- weight cvt
// dst contiguous: [Wq | Wk | Wv | Wp]
__global__ void wcvt_all(const float* __restrict__ wq, const float* __restrict__ wk,
                         const float* __restrict__ wv, const float* __restrict__ wp,
                         unsigned short* __restrict__ dst) {
    const int y = blockIdx.y;
    const float* src = (y == 0) ? wq : (y == 1) ? wk : (y == 2) ? wv : wp;
    const int i = blockIdx.x * 256 + threadIdx.x;
    float4 v = reinterpret_cast<const float4*>(src)[i];
    ushort4 o;
    o.x = f2b(v.x); o.y = f2b(v.y); o.z = f2b(v.z); o.w = f2b(v.w);
    reinterpret_cast<ushort4*>(dst + (size_t)y * (CDIM * CDIM))[i] = o;
}

// ---------------------------------------------------------------- pipelined projection
// R13-proven: 128x128 tile, BK=64, 48 KB LDS (single A buffer + double B),
// fp32 A reg-staged (cvt_pk + swizzled ds_write), counted vmcnt, raw barriers,
// 3 blocks/CU (4-wave blocks), no setprio.
template <int EPI, int NC>
__device__ __forceinline__ void proj_body(
    const float* __restrict__ A32,
    const unsigned short* __restrict__ Bp,
    const float* __restrict__ b0, const float* __restrict__ b1,
    unsigned short* __restrict__ o0, unsigned short* __restrict__ o1)
{
    constexpr int K  = CDIM;                 // 768
    constexpr int T  = NC * 128;
    constexpr int NT = K / 64;               // 12

    __shared__ __align__(16) char smem[49152];
    char* As = smem;                          // 16 KB, single buffer
    // Bs[buf] at 16384 + buf*16384

    const int tid  = threadIdx.x;
    const int lane = tid & 63;
    const int w    = tid >> 6;
    const int wr   = w >> 1, wc = w & 1;

    const int bid  = blockIdx.x;
    const int s    = (bid & 7) * (T >> 3) + (bid >> 3);
    const int colp = s % NC;
    const int rowp = s / NC;
    const int brow = rowp * 128;
    const int bcol = colp * 128;

    const int r8  = lane >> 3;
    const int c8e = ((lane & 7) ^ r8) << 3;
    const int ar  = lane >> 4;
    const int ac  = (lane & 15) << 2;
    const int fr  = lane & 15;
    const int hi4 = lane >> 4;

    f32x4 acc[4][4];
#pragma unroll
    for (int i = 0; i < 4; ++i)
#pragma unroll
        for (int j = 0; j < 4; ++j)
            acc[i][j] = (f32x4){0.f, 0.f, 0.f, 0.f};

    auto stageB = [&](int buf, int kt) {
        char* dst = smem + 16384 + buf * 16384;
#pragma unroll
        for (int g = 0; g < 4; ++g) {
            const unsigned short* src =
                Bp + (size_t)(bcol + w * 32 + g * 8 + r8) * K + kt * 64 + c8e;
            GLOAD_LDS16(src, dst + (w * 32 + g * 8) * 128);
        }
    };

    float4 fA[8];
    auto aload = [&](int kt) {
#pragma unroll
        for (int j = 0; j < 8; ++j)
            fA[j] = *(const float4*)(A32 + (size_t)(brow + w * 32 + j * 4 + ar) * K
                                     + kt * 64 + ac);
    };
    auto awrite = [&]() {
#pragma unroll
        for (int j = 0; j < 8; ++j) {
            const int row = w * 32 + j * 4 + ar;
            unsigned int p0, p1;
            asm("v_cvt_pk_bf16_f32 %0, %1, %2" : "=v"(p0) : "v"(fA[j].x), "v"(fA[j].y));
            asm("v_cvt_pk_bf16_f32 %0, %1, %2" : "=v"(p1) : "v"(fA[j].z), "v"(fA[j].w));
            uint2 pk; pk.x = p0; pk.y = p1;
            *(uint2*)(As + row * 128 + ((ac << 1) ^ ((row & 7) << 4))) = pk;
        }
    };
    auto compute = [&](int bbuf) {
        const char* Bb = smem + 16384 + bbuf * 16384;
        short8v a[4][2];
#pragma unroll
        for (int i = 0; i < 4; ++i) {
            const int row = wr * 64 + i * 16 + fr;
#pragma unroll
            for (int ks = 0; ks < 2; ++ks)
                a[i][ks] = *(const short8v*)(As + row * 128 +
                              ((((ks << 2) + hi4) ^ (row & 7)) << 4));
        }
#pragma unroll
        for (int j = 0; j < 4; ++j) {
            const int row = wc * 64 + j * 16 + fr;
            short8v bb0 = *(const short8v*)(Bb + row * 128 + ((hi4 ^ (row & 7)) << 4));
            short8v bb1 = *(const short8v*)(Bb + row * 128 + (((4 + hi4) ^ (row & 7)) << 4));
#pragma unroll
            for (int i = 0; i < 4; ++i) {
                acc[i][j] = __builtin_amdgcn_mfma_f32_16x16x32_bf16(a[i][0], bb0, acc[i][j], 0, 0, 0);
                acc[i][j] = __builtin_amdgcn_mfma_f32_16x16x32_bf16(a[i][1], bb1, acc[i][j], 0, 0, 0);
            }
        }
    };

    // prologue: A(0) -> LDS; A(1), B(0), B(1) in flight
    aload(0);
    stageB(0, 0);
    VMW4();            // drain A8(0), keep B4(0)
    awrite();
    aload(1);
    stageB(1, 1);
    LGW();
    SB();

    for (int t = 0; t < NT; ++t) {
        const int c = t & 1;
        if (t == NT - 1) { VMW0(); } else { VMW12(); }  // drain B4(t)
        SB();
        compute(c);
        SB();
        if (t < NT - 1) {
            VMW4();                         // drain A8(t+1), keep B4(t+1)
            awrite();
            if (t < NT - 2) { aload(t + 2); stageB(c, t + 2); }
            LGW();
        }
    }

    // ---------------- epilogue
    float* ep = (float*)(void*)smem + w * (16 * 68);
    const int rr = lane >> 2;
    const int cb = (lane & 3) * 4;
    const bool isV = (EPI == 1) && (colp >= 6);
    const float* bptr = (EPI == 0) ? (b0 + bcol)
                        : (isV ? (b1 + (bcol - 768)) : (b0 + bcol));
    const int colbase = ((EPI == 1 && isV) ? bcol - 768 : bcol) + wc * 64;
    unsigned short* o16 = (EPI == 1 && isV) ? o1 : o0;

    float4 bb[4];
#pragma unroll
    for (int q = 0; q < 4; ++q)
        bb[q] = *(const float4*)&bptr[wc * 64 + q * 16 + cb];

#pragma unroll
    for (int i = 0; i < 4; ++i) {
#pragma unroll
        for (int j = 0; j < 4; ++j)
#pragma unroll
            for (int r = 0; r < 4; ++r)
                ep[(hi4 * 4 + r) * 68 + j * 16 + fr] = acc[i][j][r];
#pragma unroll
        for (int q = 0; q < 4; ++q) {
            const int cc = q * 16 + cb;
            f32x4 v = *(const f32x4*)&ep[rr * 68 + cc];
            const int rg = brow + wr * 64 + i * 16 + rr;
            const float4 bq = bb[q];
            ushort4 ov;
            if (EPI == 0) {
                ov.x = f2b(phi_f((v[0] + bq.x) * QSCALE));
                ov.y = f2b(phi_f((v[1] + bq.y) * QSCALE));
                ov.z = f2b(phi_f((v[2] + bq.z) * QSCALE));
                ov.w = f2b(phi_f((v[3] + bq.w) * QSCALE));
            } else if (!isV) {
                ov.x = f2b(phi_f(v[0] + bq.x));
                ov.y = f2b(phi_f(v[1] + bq.y));
                ov.z = f2b(phi_f(v[2] + bq.z));
                ov.w = f2b(phi_f(v[3] + bq.w));
            } else {
                ov.x = f2b(v[0] + bq.x);
                ov.y = f2b(v[1] + bq.y);
                ov.z = f2b(v[2] + bq.z);
                ov.w = f2b(v[3] + bq.w);
            }
            *(ushort4*)(o16 + (size_t)rg * 768 + (colbase + cc)) = ov;
        }
    }
}

__global__ __launch_bounds__(256, 3) void g_q(
    const float* __restrict__ xq, const unsigned short* __restrict__ wq,
    const float* __restrict__ bq, unsigned short* __restrict__ qphi)
{
    proj_body<0, 6>(xq, wq, bq, nullptr, qphi, nullptr);
}

__global__ __launch_bounds__(256, 3) void g_kv(
    const float* __restrict__ xkv, const unsigned short* __restrict__ wkv,
    const float* __restrict__ bk, const float* __restrict__ bv,
    unsigned short* __restrict__ kphi, unsigned short* __restrict__ v16)
{
    proj_body<1, 12>(xkv, wkv, bk, bv, kphi, v16);
}

// ---------------------------------------------------------------- output projection
// R12/R13-proven: both operands via global_load_lds, double-buffered (64 KB),
// stage-ahead-2, counted vmcnt(8) (never 0 mid-loop), raw barriers.
__global__ __launch_bounds__(256) void g_out(
    const unsigned short* __restrict__ A16,
    const unsigned short* __restrict__ Bp,
    const float* __restrict__ bias,
    float* __restrict__ outp)
{
    constexpr int K  = CDIM;
    constexpr int NT = K / 64;               // 12
    __shared__ __align__(16) char smem[65536];
    // As[buf] at 0/16384 ; Bs[buf] at 32768/49152

    const int tid  = threadIdx.x;
    const int lane = tid & 63;
    const int w    = tid >> 6;
    const int wr   = w >> 1, wc = w & 1;

    const int bid  = blockIdx.x;
    const int s    = (bid & 7) * (768 >> 3) + (bid >> 3);
    const int colp = s % 6;
    const int rowp = s / 6;
    const int brow = rowp * 128;
    const int bcol = colp * 128;

    const int r8  = lane >> 3;
    const int c8e = ((lane & 7) ^ r8) << 3;
    const int fr  = lane & 15;
    const int hi4 = lane >> 4;

    f32x4 acc[4][4];
#pragma unroll
    for (int i = 0; i < 4; ++i)
#pragma unroll
        for (int j = 0; j < 4; ++j)
            acc[i][j] = (f32x4){0.f, 0.f, 0.f, 0.f};

    auto stageA = [&](int buf, int kt) {
        char* dst = smem + buf * 16384;
#pragma unroll
        for (int g = 0; g < 4; ++g) {
            const unsigned short* src =
                A16 + (size_t)(brow + w * 32 + g * 8 + r8) * K + kt * 64 + c8e;
            GLOAD_LDS16(src, dst + (w * 32 + g * 8) * 128);
        }
    };
    auto stageB = [&](int buf, int kt) {
        char* dst = smem + 32768 + buf * 16384;
#pragma unroll
        for (int g = 0; g < 4; ++g) {
            const unsigned short* src =
                Bp + (size_t)(bcol + w * 32 + g * 8 + r8) * K + kt * 64 + c8e;
            GLOAD_LDS16(src, dst + (w * 32 + g * 8) * 128);
        }
    };
    auto compute = [&](int buf) {
        const char* Ab = smem + buf * 16384;
        const char* Bb = smem + 32768 + buf * 16384;
        short8v a[4][2], b[4][2];
#pragma unroll
        for (int i = 0; i < 4; ++i) {
            const int row = wr * 64 + i * 16 + fr;
#pragma unroll
            for (int ks = 0; ks < 2; ++ks)
                a[i][ks] = *(const short8v*)(Ab + row * 128 +
                              ((((ks << 2) + hi4) ^ (row & 7)) << 4));
        }
#pragma unroll
        for (int j = 0; j < 4; ++j) {
            const int row = wc * 64 + j * 16 + fr;
#pragma unroll
            for (int ks = 0; ks < 2; ++ks)
                b[j][ks] = *(const short8v*)(Bb + row * 128 +
                              ((((ks << 2) + hi4) ^ (row & 7)) << 4));
        }
#pragma unroll
        for (int i = 0; i < 4; ++i)
#pragma unroll
            for (int j = 0; j < 4; ++j) {
                acc[i][j] = __builtin_amdgcn_mfma_f32_16x16x32_bf16(a[i][0], b[j][0], acc[i][j], 0, 0, 0);
                acc[i][j] = __builtin_amdgcn_mfma_f32_16x16x32_bf16(a[i][1], b[j][1], acc[i][j], 0, 0, 0);
            }
    };

    stageA(0, 0); stageB(0, 0);      // 8 outstanding
    stageA(1, 1); stageB(1, 1);      // 16 outstanding
    for (int t = 0; t < NT; ++t) {
        const int c = t & 1;
        if (t == NT - 1) { VMW0(); } else { VMW8(); }    // drain tile t's 8
        SB();
        compute(c);
        SB();
        if (t < NT - 2) { stageA(c, t + 2); stageB(c, t + 2); }  // tile t+2 -> buf c
    }

    float* ep = (float*)(void*)smem + w * (16 * 68);
    const int rr = lane >> 2;
    const int cb = (lane & 3) * 4;
    float4 bb[4];
#pragma unroll
    for (int q = 0; q < 4; ++q)
        bb[q] = *(const float4*)&bias[bcol + wc * 64 + q * 16 + cb];
#pragma unroll
    for (int i = 0; i < 4; ++i) {
#pragma unroll
        for (int j = 0; j < 4; ++j)
#pragma unroll
            for (int r = 0; r < 4; ++r)
                ep[(hi4 * 4 + r) * 68 + j * 16 + fr] = acc[i][j][r];
#pragma unroll
        for (int q = 0; q < 4; ++q) {
            const int cc = q * 16 + cb;
            f32x4 v = *(const f32x4*)&ep[rr * 68 + cc];
            const int rg = brow + wr * 64 + i * 16 + rr;
            const int cg = bcol + wc * 64 + cc;
            const float4 bq = bb[q];
            float4 ov;
            ov.x = v[0] + bq.x; ov.y = v[1] + bq.y;
            ov.z = v[2] + bq.z; ov.w = v[3] + bq.w;
            *(float4*)(outp + (size_t)rg * 768 + cg) = ov;
        }
    }
}

// ---------------------------------------------------------------- KV state
#define KVCH   128
#define KVITER 2
#define NCHUNK 16   // SEQ / (KVCH*KVITER)

__global__ __launch_bounds__(256, 3) void kv_part(
    const unsigned short* __restrict__ kphi,
    const unsigned short* __restrict__ vmat,
    float* __restrict__ part)
{
    const int bh = blockIdx.y;
    const int b  = bh / HEADS, h = bh % HEADS;
    const int c  = blockIdx.x;
    __shared__ unsigned short Kl[KVCH][HDIM];  // 16 KB (bf16)
    __shared__ float Vl[KVCH][HDIM];           // 32 KB
    const int t  = threadIdx.x;
    const int i  = t >> 2;
    const int jb = t & 3;

    float acc[16];
#pragma unroll
    for (int jj = 0; jj < 16; ++jj) acc[jj] = 0.f;
    float ksum = 0.f;

    for (int it = 0; it < KVITER; ++it) {
        const size_t rbase = (size_t)b * SEQ + (size_t)c * (KVCH * KVITER) + it * KVCH;
        __syncthreads();
        for (int l = 0; l < KVCH / 32; ++l) {
            int row = l * 32 + (t >> 3);
            int col = (t & 7) << 3;
            const size_t g = (rbase + row) * CDIM + h * HDIM + col;
            int4 kk = *(const int4*)(kphi + g);
            int4 vv = *(const int4*)(vmat + g);
            *(int4*)&Kl[row][col] = kk;                 // keep K as bf16
            const unsigned short* vp = (const unsigned short*)&vv;
            float4 lo, hi;
            lo.x = b2f(vp[0]); lo.y = b2f(vp[1]); lo.z = b2f(vp[2]); lo.w = b2f(vp[3]);
            hi.x = b2f(vp[4]); hi.y = b2f(vp[5]); hi.z = b2f(vp[6]); hi.w = b2f(vp[7]);
            *(float4*)&Vl[row][col]     = lo;
            *(float4*)&Vl[row][col + 4] = hi;
        }
        __syncthreads();
        for (int n = 0; n < KVCH; ++n) {
            float kf = b2f(Kl[n][i]);
            const float4* vr = (const float4*)&Vl[n][jb * 16];
            float4 v0 = vr[0], v1 = vr[1], v2 = vr[2], v3 = vr[3];
            acc[0]  += kf * v0.x; acc[1]  += kf * v0.y; acc[2]  += kf * v0.z; acc[3]  += kf * v0.w;
            acc[4]  += kf * v1.x; acc[5]  += kf * v1.y; acc[6]  += kf * v1.z; acc[7]  += kf * v1.w;
            acc[8]  += kf * v2.x; acc[9]  += kf * v2.y; acc[10] += kf * v2.z; acc[11] += kf * v2.w;
            acc[12] += kf * v3.x; acc[13] += kf * v3.y; acc[14] += kf * v3.z; acc[15] += kf * v3.w;
            ksum += kf;
        }
    }
    float* op = part + ((size_t)c * 48 + bh) * 4160;
#pragma unroll
    for (int jj = 0; jj < 16; ++jj) op[i * 64 + jb * 16 + jj] = acc[jj];
    if (jb == 0) op[4096 + i] = ksum;
}

__global__ void kv_finalize(const float* __restrict__ part, float* __restrict__ kv) {
    int idx = blockIdx.x * 256 + threadIdx.x;
    if (idx >= 48 * 4160) return;
    float s = 0.f;
    for (int c = 0; c < NCHUNK; ++c) s += part[(size_t)c * 48 * 4160 + idx];
    kv[idx] = s;
}

// ---------------------------------------------------------------- apply
__global__ __launch_bounds__(256) void attn_apply(
    const unsigned short* __restrict__ qphi,
    const float* __restrict__ kv,
    unsigned short* __restrict__ attn)
{
    const int h  = blockIdx.y;
    const int m0 = blockIdx.x * 64;
    const int b  = m0 >> 12;
    const int bh = b * HEADS + h;
    __shared__ float kvs[HDIM][HDIM];
    __shared__ float ksums[HDIM];
    __shared__ unsigned short ql[64][HDIM];
    const int t = threadIdx.x;
    const float* kvp = kv + (size_t)bh * 4160;
#pragma unroll
    for (int it = 0; it < 4; ++it) {
        int e = it * 1024 + t * 4;
        *(float4*)&kvs[e >> 6][e & 63] = *(const float4*)&kvp[e];
    }
    if (t < 64) ksums[t] = kvp[4096 + t];
#pragma unroll
    for (int it = 0; it < 2; ++it) {
        int row = it * 32 + (t >> 3);
        int col = (t & 7) << 3;
        *(int4*)&ql[row][col] =
            *(const int4*)(qphi + (size_t)(m0 + row) * CDIM + h * HDIM + col);
    }
    __syncthreads();

    const int r  = t >> 2;
    const int jb = t & 3;
    float acc[16];
#pragma unroll
    for (int jj = 0; jj < 16; ++jj) acc[jj] = 0.f;
    float z = 0.f;
    for (int q8 = 0; q8 < 8; ++q8) {
        short8v qv = *(const short8v*)&ql[r][q8 * 8];
#pragma unroll
        for (int dd = 0; dd < 8; ++dd) {
            float qd = b2f((unsigned short)qv[dd]);
            int d = q8 * 8 + dd;
            const float4* kr = (const float4*)&kvs[d][jb * 16];
            float4 k0 = kr[0], k1 = kr[1], k2 = kr[2], k3 = kr[3];
            acc[0]  += qd * k0.x; acc[1]  += qd * k0.y; acc[2]  += qd * k0.z; acc[3]  += qd * k0.w;
            acc[4]  += qd * k1.x; acc[5]  += qd * k1.y; acc[6]  += qd * k1.z; acc[7]  += qd * k1.w;
            acc[8]  += qd * k2.x; acc[9]  += qd * k2.y; acc[10] += qd * k2.z; acc[11] += qd * k2.w;
            acc[12] += qd * k3.x; acc[13] += qd * k3.y; acc[14] += qd * k3.z; acc[15] += qd * k3.w;
            z += qd * ksums[d];
        }
    }
    const float inv = 1.f / (z + EPSV);
    unsigned short* op = attn + (size_t)(m0 + r) * CDIM + h * HDIM + jb * 16;
#pragma unroll
    for (int jj = 0; jj < 16; ++jj) op[jj] = f2b(acc[jj] * inv);
}

// ---------------------------------------------------------------- launch
extern "C" void kernel_launch(void* const* d_in, const int* in_sizes, int n_in,
                              void* d_out, int out_size, void* d_ws, size_t ws_size,
                              hipStream_t stream)
{
    const float* x_q  = (const float*)d_in[0];
    const float* x_kv = (const float*)d_in[1];
    const float* Wq   = (const float*)d_in[2];
    const float* bq   = (const float*)d_in[3];
    const float* Wk   = (const float*)d_in[4];
    const float* bk   = (const float*)d_in[5];
    const float* Wv   = (const float*)d_in[6];
    const float* bv   = (const float*)d_in[7];
    const float* Wp   = (const float*)d_in[8];
    const float* bp   = (const float*)d_in[9];
    float* out = (float*)d_out;

    char* ws = (char*)d_ws;
    size_t off = 0;
    auto alloc = [&](size_t bytes) -> char* {
        char* p = ws + off;
        off += (bytes + 255) & ~(size_t)255;
        return p;
    };
    const size_t xelems = (size_t)MROWS * CDIM;
    const size_t welems = (size_t)CDIM * CDIM;

    // weights contiguous: [Wq, Wk, Wv, Wp]
    unsigned short* w16    = (unsigned short*)alloc(4 * welems * 2);
    unsigned short* wkv16  = w16 + welems;          // [Wk;Wv] stacked
    unsigned short* wp16   = w16 + 3 * welems;
    unsigned short* qphi   = (unsigned short*)alloc(xelems * 2);
    unsigned short* kphi   = (unsigned short*)alloc(xelems * 2);
    unsigned short* v16    = (unsigned short*)alloc(xelems * 2);
    unsigned short* attn16 = (unsigned short*)alloc(xelems * 2);
    float* part = (float*)alloc((size_t)NCHUNK * 48 * 4160 * 4);
    float* kvf  = (float*)alloc((size_t)48 * 4160 * 4);

    wcvt_all<<<dim3(576, 4), 256, 0, stream>>>(Wq, Wk, Wv, Wp, w16);

    // Q projection: pipelined, 768 blocks
    g_q<<<768, 256, 0, stream>>>(x_q, w16, bq, qphi);

    // fused K|V projection: pipelined, 1536 blocks
    g_kv<<<1536, 256, 0, stream>>>(x_kv, wkv16, bk, bv, kphi, v16);

    kv_part<<<dim3(NCHUNK, 48), 256, 0, stream>>>(kphi, v16, part);
    kv_finalize<<<(48 * 4160 + 255) / 256, 256, 0, stream>>>(part, kvf);
    attn_apply<<<dim3(MROWS / 64, HEADS), 256, 0, stream>>>(qphi, kvf, attn16);

    // output projection: pipelined both-gload, 768 blocks
    g_out<<<768, 256, 0, stream>>>(attn16, wp16, bp, out);
}